// Round 8
// baseline (153.487 us; speedup 1.0000x reference)
//
#include <hip/hip_runtime.h>

typedef __attribute__((ext_vector_type(8))) short short8;
typedef __attribute__((ext_vector_type(4))) float f32x4;
typedef __attribute__((ext_vector_type(16))) float f32x16;
typedef __attribute__((ext_vector_type(4))) unsigned short ushort4v;
typedef __attribute__((ext_vector_type(4))) unsigned int uint4v;
typedef __attribute__((ext_vector_type(2))) unsigned int uint2v;

constexpr int Nc = 2048, Kc = 1024;
constexpr float LOG2E = 1.4426950408889634f;

__device__ inline unsigned short f2bf(float f) {
  unsigned u = __builtin_bit_cast(unsigned, f);
  u = u + 0x7FFFu + ((u >> 16) & 1u);
  return (unsigned short)(u >> 16);
}
__device__ inline float bf2f(unsigned short h) {
  unsigned u = ((unsigned)h) << 16;
  return __builtin_bit_cast(float, u);
}
__device__ inline float fexp2(float x) {
  float r;
  asm("v_exp_f32 %0, %1" : "=v"(r) : "v"(x));
  return r;
}
__device__ inline unsigned cvt_pk_bf16(float lo, float hi) {
  unsigned r;
  asm("v_cvt_pk_bf16_f32 %0, %1, %2" : "=v"(r) : "v"(lo), "v"(hi));
  return r;
}

__device__ inline void gload_lds16(const void* g, void* l) {
  __builtin_amdgcn_global_load_lds(
      (const __attribute__((address_space(1))) unsigned int*)g,
      (__attribute__((address_space(3))) unsigned int*)l, 16, 0, 0);
}

// ---------------- fp32 -> bf16 convert, all 4 inputs in one launch ----------------
__global__ __launch_bounds__(256) void cvt_all(const float* __restrict__ x,
                                               const float* __restrict__ wqk,
                                               const float* __restrict__ wv,
                                               const float* __restrict__ wo,
                                               unsigned short* __restrict__ xb,
                                               unsigned short* __restrict__ wqkb,
                                               unsigned short* __restrict__ wvb,
                                               unsigned short* __restrict__ wob) {
  int bid = blockIdx.x;
  const float* src;
  unsigned short* dst;
  int i;
  if (bid < 2048) {
    src = x; dst = xb; i = bid * 256 + threadIdx.x;
  } else {
    int k = bid - 2048;
    int which = k >> 9, sub = k & 511;
    src = (which == 0) ? wqk : (which == 1) ? wv : wo;
    dst = (which == 0) ? wqkb : (which == 1) ? wvb : wob;
    i = sub * 256 + threadIdx.x;
  }
  const float4* s = reinterpret_cast<const float4*>(src) + 2 * (size_t)i;
  float4 a = s[0], b = s[1];
  short8 o;
  o[0] = (short)f2bf(a.x); o[1] = (short)f2bf(a.y); o[2] = (short)f2bf(a.z); o[3] = (short)f2bf(a.w);
  o[4] = (short)f2bf(b.x); o[5] = (short)f2bf(b.y); o[6] = (short)f2bf(b.z); o[7] = (short)f2bf(b.w);
  *reinterpret_cast<short8*>(dst + (size_t)i * 8) = o;
}

// ------- merged projection GEMM + fused q2: qk = x@Wqk^T (B,H,N,d), v^T (B,H,d,N) -------
__global__ __launch_bounds__(256) void gemm_proj(const unsigned short* __restrict__ A,
                                                 const unsigned short* __restrict__ Wqk,
                                                 const unsigned short* __restrict__ Wv,
                                                 unsigned short* __restrict__ qk_out,
                                                 unsigned short* __restrict__ vt_out,
                                                 float* __restrict__ q2l) {
  __shared__ unsigned short As[128 * 64];
  __shared__ unsigned short Bs[128 * 64];
  const int tid = threadIdx.x;
  const int bm = blockIdx.x & 31;
  const int bn = blockIdx.x >> 5;      // 0..15
  const bool isV = bn >= 8;
  const int lane = tid & 63, wid = tid >> 6;
  const int wr = wid >> 1, wc = wid & 1;
  const int lr = lane & 15, lg = lane >> 4;

  f32x4 acc[4][4] = {};

  const unsigned short* Abase = A + (size_t)bm * 128 * Kc;
  const unsigned short* Wbase = (isV ? Wv + (size_t)(bn - 8) * 128 * Kc
                                     : Wqk + (size_t)bn * 128 * Kc);

  for (int kt = 0; kt < Kc / 64; ++kt) {
    __syncthreads();
#pragma unroll
    for (int r = 0; r < 4; ++r) {
      int idx = r * 256 + tid;
      int row = idx >> 3, cc = idx & 7;
      int cs = cc ^ (row & 7);
      gload_lds16(Abase + (size_t)row * Kc + kt * 64 + cs * 8, &As[(r * 256 + wid * 64) * 8]);
      gload_lds16(Wbase + (size_t)row * Kc + kt * 64 + cs * 8, &Bs[(r * 256 + wid * 64) * 8]);
    }
    __syncthreads();

    short8 af[4][2], bfv[4][2];
#pragma unroll
    for (int m = 0; m < 4; ++m) {
      int row = wr * 64 + m * 16 + lr;
#pragma unroll
      for (int kh = 0; kh < 2; ++kh) {
        int cs = (kh * 4 + lg) ^ (row & 7);
        af[m][kh] = *reinterpret_cast<const short8*>(&As[row * 64 + cs * 8]);
      }
    }
#pragma unroll
    for (int n = 0; n < 4; ++n) {
      int row = wc * 64 + n * 16 + lr;
#pragma unroll
      for (int kh = 0; kh < 2; ++kh) {
        int cs = (kh * 4 + lg) ^ (row & 7);
        bfv[n][kh] = *reinterpret_cast<const short8*>(&Bs[row * 64 + cs * 8]);
      }
    }
#pragma unroll
    for (int kh = 0; kh < 2; ++kh)
#pragma unroll
      for (int m = 0; m < 4; ++m)
#pragma unroll
        for (int n = 0; n < 4; ++n)
          acc[m][n] = __builtin_amdgcn_mfma_f32_16x16x32_bf16(af[m][kh], bfv[n][kh], acc[m][n], 0, 0, 0);
  }

#pragma unroll
  for (int m = 0; m < 4; ++m) {
#pragma unroll
    for (int n = 0; n < 4; ++n) {
      int grow0 = bm * 128 + wr * 64 + m * 16 + lg * 4;
      int b = grow0 >> 11, nn0 = grow0 & 2047;
      if (isV) {
        int gcol = (bn - 8) * 128 + wc * 64 + n * 16 + lr;
        int h = gcol >> 6, dd = gcol & 63;
        ushort4v pk;
#pragma unroll
        for (int r = 0; r < 4; ++r) pk[r] = f2bf(acc[m][n][r]);
        *reinterpret_cast<ushort4v*>(&vt_out[(((size_t)(b * 16 + h)) * 64 + dd) * 2048 + nn0]) = pk;
      } else {
        int gcol = bn * 128 + wc * 64 + n * 16 + lr;
        int h = gcol >> 6, dd = gcol & 63;
#pragma unroll
        for (int r = 0; r < 4; ++r)
          qk_out[(((size_t)(b * 16 + h)) * 2048 + nn0 + r) * 64 + dd] = f2bf(acc[m][n][r]);
      }
    }
  }

  // fused q2: for qk blocks, wave wc holds all 64 d-cols of head h=2bn+wc
  if (!isV) {
    const int h = 2 * bn + wc;
#pragma unroll
    for (int m = 0; m < 4; ++m) {
#pragma unroll
      for (int r = 0; r < 4; ++r) {
        float ss = 0.f;
#pragma unroll
        for (int n = 0; n < 4; ++n) ss += acc[m][n][r] * acc[m][n][r];
        ss += __shfl_xor(ss, 1);
        ss += __shfl_xor(ss, 2);
        ss += __shfl_xor(ss, 4);
        ss += __shfl_xor(ss, 8);
        if (lr == 0) {
          int grow = bm * 128 + wr * 64 + m * 16 + lg * 4 + r;
          int b = grow >> 11, nn = grow & 2047;
          q2l[((size_t)(b * 16 + h)) * 2048 + nn] = ss * LOG2E;
        }
      }
    }
  }
}

// ------- output GEMM: out[m][e] = sum_k w[m][k] * Wout[e][k], fp32 out -------
__global__ __launch_bounds__(256) void gemm_out(const unsigned short* __restrict__ A,
                                                const unsigned short* __restrict__ W,
                                                float* __restrict__ out) {
  __shared__ unsigned short As[128 * 64];
  __shared__ unsigned short Bs[64 * 64];
  const int tid = threadIdx.x;
  const int bm = blockIdx.x & 31;
  const int bn = blockIdx.x >> 5;      // 0..15
  const int lane = tid & 63, wid = tid >> 6;
  const int wr = wid >> 1, wc = wid & 1;
  const int lr = lane & 15, lg = lane >> 4;

  f32x4 acc[4][2] = {};

  const unsigned short* Abase = A + (size_t)bm * 128 * Kc;
  const unsigned short* Wbase = W + (size_t)bn * 64 * Kc;

  for (int kt = 0; kt < Kc / 64; ++kt) {
    __syncthreads();
#pragma unroll
    for (int r = 0; r < 4; ++r) {
      int idx = r * 256 + tid;
      int row = idx >> 3, cc = idx & 7;
      int cs = cc ^ (row & 7);
      gload_lds16(Abase + (size_t)row * Kc + kt * 64 + cs * 8, &As[(r * 256 + wid * 64) * 8]);
    }
#pragma unroll
    for (int r = 0; r < 2; ++r) {
      int idx = r * 256 + tid;
      int row = idx >> 3, cc = idx & 7;
      int cs = cc ^ (row & 7);
      gload_lds16(Wbase + (size_t)row * Kc + kt * 64 + cs * 8, &Bs[(r * 256 + wid * 64) * 8]);
    }
    __syncthreads();

    short8 af[4][2], bfv[2][2];
#pragma unroll
    for (int m = 0; m < 4; ++m) {
      int row = wr * 64 + m * 16 + lr;
#pragma unroll
      for (int kh = 0; kh < 2; ++kh) {
        int cs = (kh * 4 + lg) ^ (row & 7);
        af[m][kh] = *reinterpret_cast<const short8*>(&As[row * 64 + cs * 8]);
      }
    }
#pragma unroll
    for (int n = 0; n < 2; ++n) {
      int row = wc * 32 + n * 16 + lr;
#pragma unroll
      for (int kh = 0; kh < 2; ++kh) {
        int cs = (kh * 4 + lg) ^ (row & 7);
        bfv[n][kh] = *reinterpret_cast<const short8*>(&Bs[row * 64 + cs * 8]);
      }
    }
#pragma unroll
    for (int kh = 0; kh < 2; ++kh)
#pragma unroll
      for (int m = 0; m < 4; ++m)
#pragma unroll
        for (int n = 0; n < 2; ++n)
          acc[m][n] = __builtin_amdgcn_mfma_f32_16x16x32_bf16(af[m][kh], bfv[n][kh], acc[m][n], 0, 0, 0);
  }

#pragma unroll
  for (int m = 0; m < 4; ++m)
#pragma unroll
    for (int n = 0; n < 2; ++n)
#pragma unroll
      for (int r = 0; r < 4; ++r) {
        int grow = bm * 128 + wr * 64 + m * 16 + lg * 4 + r;
        int gcol = bn * 64 + wc * 32 + n * 16 + lr;
        out[(size_t)grow * 1024 + gcol] = acc[m][n][r];
      }
}

// ---------------- fused distance-attention ----------------
// Wave owns 64 q-rows (2 x 32). Serial per-q-block softmax (low reg liveness);
// den via per-lane adds + shfl_xor(32) (S^T layout: lane holds q-row=lo).
// launch_bounds(256,3): cap total regs ~170 -> 3 waves/SIMD.
// PARTIAL: K-split x4 (grid 1024, 8 tiles each), bf16-packed num partials.
template<bool PARTIAL>
__global__ __launch_bounds__(256, 3) void attn_kernel(const unsigned short* __restrict__ qk,
                                                      const unsigned short* __restrict__ vt,
                                                      const float* __restrict__ q2lg_,
                                                      unsigned short* __restrict__ wout,
                                                      unsigned* __restrict__ num32,
                                                      float* __restrict__ denP) {
  __shared__ unsigned short Ks[2][64 * 64];
  __shared__ unsigned short Vs[2][64 * 64];
  __shared__ float q2L[2][64];
  __shared__ float invL[4][64];

  const int tid = threadIdx.x;
  const int chunk = PARTIAL ? 128 : 32;
  const int orig = (blockIdx.x & 7) * chunk + (blockIdx.x >> 3);
  const int half = PARTIAL ? (orig >> 8) : 0;
  const int rest = PARTIAL ? (orig & 255) : orig;
  const int bh = rest >> 3;          // 0..31
  const int qt = rest & 7;           // 8 q-tiles of 256 rows
  const int b = bh >> 4, h = bh & 15;
  const unsigned short* Qg = qk + (size_t)bh * Nc * 64;
  const unsigned short* Vg = vt + (size_t)bh * 64 * Nc;
  const float* q2lg = q2lg_ + (size_t)bh * Nc;
  const int lane = tid & 63, wid = tid >> 6;
  const int lo = lane & 31, hi = lane >> 5;

  const int qbase = qt * 256 + wid * 64;   // wave owns rows [qbase, qbase+64)
  const int kt0 = half * 8;
  const int ktn = PARTIAL ? 8 : 32;

  short8 qf0[4], qf1[4];
#pragma unroll
  for (int kk = 0; kk < 4; ++kk) {
    qf0[kk] = *reinterpret_cast<const short8*>(
        Qg + (size_t)(qbase + lo) * 64 + kk * 16 + hi * 8);
    qf1[kk] = *reinterpret_cast<const short8*>(
        Qg + (size_t)(qbase + 32 + lo) * 64 + kk * 16 + hi * 8);
  }
  const float q2l_r0 = q2lg[qbase + lo];
  const float q2l_r1 = q2lg[qbase + 32 + lo];

  f32x16 w00 = {}, w01 = {}, w10 = {}, w11 = {};
  float den0 = 0.f, den1 = 0.f;

  auto stage = [&](int kt, int s) {
#pragma unroll
    for (int r = 0; r < 2; ++r) {
      int idx = r * 256 + tid;
      int row = idx >> 3, cc = idx & 7;
      int cs = cc ^ (row & 7);
      gload_lds16(Qg + (size_t)(kt * 64 + row) * 64 + cs * 8,
                  &Ks[s][(r * 256 + wid * 64) * 8]);
      gload_lds16(Vg + (size_t)row * Nc + kt * 64 + cs * 8,
                  &Vs[s][(r * 256 + wid * 64) * 8]);
    }
    if (tid < 16) gload_lds16(q2lg + kt * 64 + tid * 4, &q2L[s][0]);
  };

  stage(kt0, 0);
  __syncthreads();

  for (int t = 0; t < ktn; ++t) {
    const int kt = kt0 + t;
    const int cur = t & 1;
    if (t + 1 < ktn) stage(kt + 1, cur ^ 1);

#pragma unroll
    for (int kg = 0; kg < 2; ++kg) {
      short8 kf[4];
#pragma unroll
      for (int kk = 0; kk < 4; ++kk) {
        int row = kg * 32 + lo;
        int c = (kk * 2 + hi) ^ (row & 7);
        kf[kk] = *reinterpret_cast<const short8*>(&Ks[cur][row * 64 + c * 8]);
      }

      unsigned pkA[8], pkB[8];
      {  // q-block 0
        f32x16 s = {};
        __builtin_amdgcn_s_setprio(1);
#pragma unroll
        for (int kk = 0; kk < 4; ++kk)
          s = __builtin_amdgcn_mfma_f32_32x32x16_bf16(kf[kk], qf0[kk], s, 0, 0, 0);
        __builtin_amdgcn_s_setprio(0);
#pragma unroll
        for (int q = 0; q < 4; ++q) {
          float4 k2q = *reinterpret_cast<const float4*>(&q2L[cur][kg * 32 + q * 8 + hi * 4]);
          float g[4];
#pragma unroll
          for (int rr = 0; rr < 4; ++rr) {
            float k2 = (rr == 0) ? k2q.x : (rr == 1) ? k2q.y : (rr == 2) ? k2q.z : k2q.w;
            g[rr] = fexp2(fmaf(s[q * 4 + rr], 2.0f * LOG2E, -(q2l_r0 + k2)));
            den0 += g[rr];
          }
          pkA[q * 2]     = cvt_pk_bf16(g[0], g[1]);
          pkA[q * 2 + 1] = cvt_pk_bf16(g[2], g[3]);
        }
      }
      {  // q-block 1
        f32x16 s = {};
        __builtin_amdgcn_s_setprio(1);
#pragma unroll
        for (int kk = 0; kk < 4; ++kk)
          s = __builtin_amdgcn_mfma_f32_32x32x16_bf16(kf[kk], qf1[kk], s, 0, 0, 0);
        __builtin_amdgcn_s_setprio(0);
#pragma unroll
        for (int q = 0; q < 4; ++q) {
          float4 k2q = *reinterpret_cast<const float4*>(&q2L[cur][kg * 32 + q * 8 + hi * 4]);
          float g[4];
#pragma unroll
          for (int rr = 0; rr < 4; ++rr) {
            float k2 = (rr == 0) ? k2q.x : (rr == 1) ? k2q.y : (rr == 2) ? k2q.z : k2q.w;
            g[rr] = fexp2(fmaf(s[q * 4 + rr], 2.0f * LOG2E, -(q2l_r1 + k2)));
            den1 += g[rr];
          }
          pkB[q * 2]     = cvt_pk_bf16(g[0], g[1]);
          pkB[q * 2 + 1] = cvt_pk_bf16(g[2], g[3]);
        }
      }

      // PV per 16-key sub-window; V-frags shared by both q-blocks.
      // permlane32_swap(a,b) -> {[a_lo,b_lo],[a_hi,b_hi]} (lane halves).
#pragma unroll
      for (int kkl = 0; kkl < 2; ++kkl) {
        uint2v r00 = __builtin_amdgcn_permlane32_swap(pkA[4 * kkl + 0], pkA[4 * kkl + 2], false, false);
        uint2v r01 = __builtin_amdgcn_permlane32_swap(pkA[4 * kkl + 1], pkA[4 * kkl + 3], false, false);
        uint2v r10 = __builtin_amdgcn_permlane32_swap(pkB[4 * kkl + 0], pkB[4 * kkl + 2], false, false);
        uint2v r11 = __builtin_amdgcn_permlane32_swap(pkB[4 * kkl + 1], pkB[4 * kkl + 3], false, false);
        uint4v u0; u0[0] = r00[0]; u0[1] = r01[0]; u0[2] = r00[1]; u0[3] = r01[1];
        uint4v u1; u1[0] = r10[0]; u1[1] = r11[0]; u1[2] = r10[1]; u1[3] = r11[1];
        short8 pa0 = __builtin_bit_cast(short8, u0);
        short8 pa1 = __builtin_bit_cast(short8, u1);

        __builtin_amdgcn_s_setprio(1);
#pragma unroll
        for (int dt = 0; dt < 2; ++dt) {
          int row = dt * 32 + lo;
          int c = (kg * 4 + kkl * 2 + hi) ^ (row & 7);
          short8 vfr = *reinterpret_cast<const short8*>(&Vs[cur][row * 64 + c * 8]);
          if (dt == 0) {
            w00 = __builtin_amdgcn_mfma_f32_32x32x16_bf16(pa0, vfr, w00, 0, 0, 0);
            w10 = __builtin_amdgcn_mfma_f32_32x32x16_bf16(pa1, vfr, w10, 0, 0, 0);
          } else {
            w01 = __builtin_amdgcn_mfma_f32_32x32x16_bf16(pa0, vfr, w01, 0, 0, 0);
            w11 = __builtin_amdgcn_mfma_f32_32x32x16_bf16(pa1, vfr, w11, 0, 0, 0);
          }
        }
        __builtin_amdgcn_s_setprio(0);
      }
    }
    __syncthreads();
  }

  den0 += __shfl_xor(den0, 32);
  den1 += __shfl_xor(den1, 32);

  if constexpr (PARTIAL) {
    unsigned* numh = num32 + (size_t)half * 65536 * 32;
    float* denh = denP + (size_t)half * 65536;
    const int rowb = bh * Nc + qbase;
    if (hi == 0) {
      denh[rowb + lo] = den0;
      denh[rowb + 32 + lo] = den1;
    }
#pragma unroll
    for (int reg = 0; reg < 16; ++reg) {
      int crow = (reg & 3) + 8 * (reg >> 2) + 4 * hi;
      numh[(size_t)(rowb + crow) * 32 + lo]      = cvt_pk_bf16(w00[reg], w01[reg]);
      numh[(size_t)(rowb + 32 + crow) * 32 + lo] = cvt_pk_bf16(w10[reg], w11[reg]);
    }
  } else {
    if (hi == 0) {
      invL[wid][lo]      = __builtin_amdgcn_rcpf(den0);
      invL[wid][32 + lo] = __builtin_amdgcn_rcpf(den1);
    }
    __syncthreads();
#pragma unroll
    for (int reg = 0; reg < 16; ++reg) {
      int crow = (reg & 3) + 8 * (reg >> 2) + 4 * hi;
      float iv0 = invL[wid][crow];
      float iv1 = invL[wid][32 + crow];
      size_t base0 = ((size_t)b * Nc + qbase + crow) * 1024 + h * 64 + lo;
      size_t base1 = ((size_t)b * Nc + qbase + 32 + crow) * 1024 + h * 64 + lo;
      wout[base0]      = f2bf(w00[reg] * iv0);
      wout[base0 + 32] = f2bf(w01[reg] * iv0);
      wout[base1]      = f2bf(w10[reg] * iv1);
      wout[base1 + 32] = f2bf(w11[reg] * iv1);
    }
  }
}

// -------- combine 4 partials: w = sum(num)/sum(den), scatter to (B,N,D) bf16 --------
__global__ __launch_bounds__(256) void combine_kernel(const unsigned* __restrict__ num32,
                                                      const float* __restrict__ denP,
                                                      unsigned short* __restrict__ wout) {
  int gid = blockIdx.x * 256 + threadIdx.x;   // 262144 threads
  int row = gid >> 2, quad = gid & 3;
  float dsum = denP[row] + denP[65536 + row] + denP[131072 + row] + denP[196608 + row];
  float iv = 1.0f / dsum;
  float lo_[8] = {}, hi_[8] = {};
#pragma unroll
  for (int p = 0; p < 4; ++p) {
    const uint4v* np = reinterpret_cast<const uint4v*>(
        num32 + ((size_t)p * 65536 + row) * 32 + quad * 8);
    uint4v a = np[0], c = np[1];
#pragma unroll
    for (int j = 0; j < 4; ++j) {
      unsigned u = a[j];
      lo_[j] += bf2f((unsigned short)(u & 0xffff));
      hi_[j] += bf2f((unsigned short)(u >> 16));
      unsigned v = c[j];
      lo_[4 + j] += bf2f((unsigned short)(v & 0xffff));
      hi_[4 + j] += bf2f((unsigned short)(v >> 16));
    }
  }
  short8 o1, o2;
#pragma unroll
  for (int j = 0; j < 8; ++j) {
    o1[j] = (short)f2bf(lo_[j] * iv);
    o2[j] = (short)f2bf(hi_[j] * iv);
  }
  int bh = row >> 11, nn = row & 2047;
  int b = bh >> 4, h = bh & 15;
  size_t base = ((size_t)b * Nc + nn) * 1024 + h * 64;
  *reinterpret_cast<short8*>(&wout[base + quad * 8]) = o1;
  *reinterpret_cast<short8*>(&wout[base + 32 + quad * 8]) = o2;
}

extern "C" void kernel_launch(void* const* d_in, const int* in_sizes, int n_in,
                              void* d_out, int out_size, void* d_ws, size_t ws_size,
                              hipStream_t stream) {
  const float* x    = (const float*)d_in[0];
  const float* Wqk  = (const float*)d_in[1];
  const float* Wv   = (const float*)d_in[2];
  const float* Wout = (const float*)d_in[3];
  float* out = (float*)d_out;
  char* ws = (char*)d_ws;

  unsigned short* x_bf    = (unsigned short*)(ws + 0);          //  8 MB (dead after gemm_proj)
  unsigned short* wqk_bf  = (unsigned short*)(ws + 8388608);    //  2 MB
  unsigned short* wv_bf   = (unsigned short*)(ws + 10485760);   //  2 MB
  unsigned short* wout_bf = (unsigned short*)(ws + 12582912);   //  2 MB
  unsigned short* qk_buf  = (unsigned short*)(ws + 14680064);   //  8 MB (B,H,N,d)
  unsigned short* vt_buf  = (unsigned short*)(ws + 23068672);   //  8 MB (B,H,d,N)
  float*          q2l_buf = (float*)        (ws + 31457280);    // 256 KB
  unsigned short* w_buf   = (unsigned short*)(ws + 31719424);   //  8 MB (B,N,D)
  unsigned*       num_buf = (unsigned*)     (ws + 40108032);    // 32 MB (4 halves, bf16-packed)
  float*          den_buf = (float*)        (ws + 0);           //  1 MB (reuses x_bf region)
  const size_t need_split = 73662464;

  cvt_all<<<3584, 256, 0, stream>>>(x, Wqk, Wv, Wout, x_bf, wqk_bf, wv_bf, wout_bf);

  gemm_proj<<<512, 256, 0, stream>>>(x_bf, wqk_bf, wv_bf, qk_buf, vt_buf, q2l_buf);

  if (ws_size >= need_split) {
    attn_kernel<true><<<1024, 256, 0, stream>>>(qk_buf, vt_buf, q2l_buf, nullptr, num_buf, den_buf);
    combine_kernel<<<1024, 256, 0, stream>>>(num_buf, den_buf, w_buf);
  } else {
    attn_kernel<false><<<256, 256, 0, stream>>>(qk_buf, vt_buf, q2l_buf, w_buf, nullptr, nullptr);
  }

  gemm_out<<<512, 256, 0, stream>>>(w_buf, wout_bf, out);
}

// Round 9
// 109.820 us; speedup vs baseline: 1.3976x; 1.3976x over previous
//
#include <hip/hip_runtime.h>

typedef __attribute__((ext_vector_type(8))) short short8;
typedef __attribute__((ext_vector_type(4))) float f32x4;
typedef __attribute__((ext_vector_type(16))) float f32x16;
typedef __attribute__((ext_vector_type(4))) unsigned short ushort4v;
typedef __attribute__((ext_vector_type(4))) unsigned int uint4v;
typedef __attribute__((ext_vector_type(2))) unsigned int uint2v;

constexpr int Nc = 2048, Kc = 1024;
constexpr float LOG2E = 1.4426950408889634f;

__device__ inline unsigned short f2bf(float f) {
  unsigned u = __builtin_bit_cast(unsigned, f);
  u = u + 0x7FFFu + ((u >> 16) & 1u);
  return (unsigned short)(u >> 16);
}
__device__ inline float bf2f(unsigned short h) {
  unsigned u = ((unsigned)h) << 16;
  return __builtin_bit_cast(float, u);
}
__device__ inline float fexp2(float x) {
  float r;
  asm("v_exp_f32 %0, %1" : "=v"(r) : "v"(x));
  return r;
}
__device__ inline unsigned cvt_pk_bf16(float lo, float hi) {
  unsigned r;
  asm("v_cvt_pk_bf16_f32 %0, %1, %2" : "=v"(r) : "v"(lo), "v"(hi));
  return r;
}

__device__ inline void gload_lds16(const void* g, void* l) {
  __builtin_amdgcn_global_load_lds(
      (const __attribute__((address_space(1))) unsigned int*)g,
      (__attribute__((address_space(3))) unsigned int*)l, 16, 0, 0);
}

// ---------------- fp32 -> bf16 convert, all 4 inputs in one launch ----------------
__global__ __launch_bounds__(256) void cvt_all(const float* __restrict__ x,
                                               const float* __restrict__ wqk,
                                               const float* __restrict__ wv,
                                               const float* __restrict__ wo,
                                               unsigned short* __restrict__ xb,
                                               unsigned short* __restrict__ wqkb,
                                               unsigned short* __restrict__ wvb,
                                               unsigned short* __restrict__ wob) {
  int bid = blockIdx.x;
  const float* src;
  unsigned short* dst;
  int i;
  if (bid < 2048) {
    src = x; dst = xb; i = bid * 256 + threadIdx.x;
  } else {
    int k = bid - 2048;
    int which = k >> 9, sub = k & 511;
    src = (which == 0) ? wqk : (which == 1) ? wv : wo;
    dst = (which == 0) ? wqkb : (which == 1) ? wvb : wob;
    i = sub * 256 + threadIdx.x;
  }
  const float4* s = reinterpret_cast<const float4*>(src) + 2 * (size_t)i;
  float4 a = s[0], b = s[1];
  short8 o;
  o[0] = (short)f2bf(a.x); o[1] = (short)f2bf(a.y); o[2] = (short)f2bf(a.z); o[3] = (short)f2bf(a.w);
  o[4] = (short)f2bf(b.x); o[5] = (short)f2bf(b.y); o[6] = (short)f2bf(b.z); o[7] = (short)f2bf(b.w);
  *reinterpret_cast<short8*>(dst + (size_t)i * 8) = o;
}

// ------- merged projection GEMM + fused q2: qk = x@Wqk^T (B,H,N,d), v^T (B,H,d,N) -------
__global__ __launch_bounds__(256) void gemm_proj(const unsigned short* __restrict__ A,
                                                 const unsigned short* __restrict__ Wqk,
                                                 const unsigned short* __restrict__ Wv,
                                                 unsigned short* __restrict__ qk_out,
                                                 unsigned short* __restrict__ vt_out,
                                                 float* __restrict__ q2l) {
  __shared__ unsigned short As[128 * 64];
  __shared__ unsigned short Bs[128 * 64];
  const int tid = threadIdx.x;
  const int bm = blockIdx.x & 31;
  const int bn = blockIdx.x >> 5;      // 0..15
  const bool isV = bn >= 8;
  const int lane = tid & 63, wid = tid >> 6;
  const int wr = wid >> 1, wc = wid & 1;
  const int lr = lane & 15, lg = lane >> 4;

  f32x4 acc[4][4] = {};

  const unsigned short* Abase = A + (size_t)bm * 128 * Kc;
  const unsigned short* Wbase = (isV ? Wv + (size_t)(bn - 8) * 128 * Kc
                                     : Wqk + (size_t)bn * 128 * Kc);

  for (int kt = 0; kt < Kc / 64; ++kt) {
    __syncthreads();
#pragma unroll
    for (int r = 0; r < 4; ++r) {
      int idx = r * 256 + tid;
      int row = idx >> 3, cc = idx & 7;
      int cs = cc ^ (row & 7);
      gload_lds16(Abase + (size_t)row * Kc + kt * 64 + cs * 8, &As[(r * 256 + wid * 64) * 8]);
      gload_lds16(Wbase + (size_t)row * Kc + kt * 64 + cs * 8, &Bs[(r * 256 + wid * 64) * 8]);
    }
    __syncthreads();

    short8 af[4][2], bfv[4][2];
#pragma unroll
    for (int m = 0; m < 4; ++m) {
      int row = wr * 64 + m * 16 + lr;
#pragma unroll
      for (int kh = 0; kh < 2; ++kh) {
        int cs = (kh * 4 + lg) ^ (row & 7);
        af[m][kh] = *reinterpret_cast<const short8*>(&As[row * 64 + cs * 8]);
      }
    }
#pragma unroll
    for (int n = 0; n < 4; ++n) {
      int row = wc * 64 + n * 16 + lr;
#pragma unroll
      for (int kh = 0; kh < 2; ++kh) {
        int cs = (kh * 4 + lg) ^ (row & 7);
        bfv[n][kh] = *reinterpret_cast<const short8*>(&Bs[row * 64 + cs * 8]);
      }
    }
#pragma unroll
    for (int kh = 0; kh < 2; ++kh)
#pragma unroll
      for (int m = 0; m < 4; ++m)
#pragma unroll
        for (int n = 0; n < 4; ++n)
          acc[m][n] = __builtin_amdgcn_mfma_f32_16x16x32_bf16(af[m][kh], bfv[n][kh], acc[m][n], 0, 0, 0);
  }

#pragma unroll
  for (int m = 0; m < 4; ++m) {
#pragma unroll
    for (int n = 0; n < 4; ++n) {
      int grow0 = bm * 128 + wr * 64 + m * 16 + lg * 4;
      int b = grow0 >> 11, nn0 = grow0 & 2047;
      if (isV) {
        int gcol = (bn - 8) * 128 + wc * 64 + n * 16 + lr;
        int h = gcol >> 6, dd = gcol & 63;
        ushort4v pk;
#pragma unroll
        for (int r = 0; r < 4; ++r) pk[r] = f2bf(acc[m][n][r]);
        *reinterpret_cast<ushort4v*>(&vt_out[(((size_t)(b * 16 + h)) * 64 + dd) * 2048 + nn0]) = pk;
      } else {
        int gcol = bn * 128 + wc * 64 + n * 16 + lr;
        int h = gcol >> 6, dd = gcol & 63;
#pragma unroll
        for (int r = 0; r < 4; ++r)
          qk_out[(((size_t)(b * 16 + h)) * 2048 + nn0 + r) * 64 + dd] = f2bf(acc[m][n][r]);
      }
    }
  }

  // fused q2: for qk blocks, wave wc holds all 64 d-cols of head h=2bn+wc
  if (!isV) {
    const int h = 2 * bn + wc;
#pragma unroll
    for (int m = 0; m < 4; ++m) {
#pragma unroll
      for (int r = 0; r < 4; ++r) {
        float ss = 0.f;
#pragma unroll
        for (int n = 0; n < 4; ++n) ss += acc[m][n][r] * acc[m][n][r];
        ss += __shfl_xor(ss, 1);
        ss += __shfl_xor(ss, 2);
        ss += __shfl_xor(ss, 4);
        ss += __shfl_xor(ss, 8);
        if (lr == 0) {
          int grow = bm * 128 + wr * 64 + m * 16 + lg * 4 + r;
          int b = grow >> 11, nn = grow & 2047;
          q2l[((size_t)(b * 16 + h)) * 2048 + nn] = ss * LOG2E;
        }
      }
    }
  }
}

// ------- output GEMM: out[m][e] = sum_k w[m][k] * Wout[e][k], fp32 out -------
__global__ __launch_bounds__(256) void gemm_out(const unsigned short* __restrict__ A,
                                                const unsigned short* __restrict__ W,
                                                float* __restrict__ out) {
  __shared__ unsigned short As[128 * 64];
  __shared__ unsigned short Bs[64 * 64];
  const int tid = threadIdx.x;
  const int bm = blockIdx.x & 31;
  const int bn = blockIdx.x >> 5;      // 0..15
  const int lane = tid & 63, wid = tid >> 6;
  const int wr = wid >> 1, wc = wid & 1;
  const int lr = lane & 15, lg = lane >> 4;

  f32x4 acc[4][2] = {};

  const unsigned short* Abase = A + (size_t)bm * 128 * Kc;
  const unsigned short* Wbase = W + (size_t)bn * 64 * Kc;

  for (int kt = 0; kt < Kc / 64; ++kt) {
    __syncthreads();
#pragma unroll
    for (int r = 0; r < 4; ++r) {
      int idx = r * 256 + tid;
      int row = idx >> 3, cc = idx & 7;
      int cs = cc ^ (row & 7);
      gload_lds16(Abase + (size_t)row * Kc + kt * 64 + cs * 8, &As[(r * 256 + wid * 64) * 8]);
    }
#pragma unroll
    for (int r = 0; r < 2; ++r) {
      int idx = r * 256 + tid;
      int row = idx >> 3, cc = idx & 7;
      int cs = cc ^ (row & 7);
      gload_lds16(Wbase + (size_t)row * Kc + kt * 64 + cs * 8, &Bs[(r * 256 + wid * 64) * 8]);
    }
    __syncthreads();

    short8 af[4][2], bfv[2][2];
#pragma unroll
    for (int m = 0; m < 4; ++m) {
      int row = wr * 64 + m * 16 + lr;
#pragma unroll
      for (int kh = 0; kh < 2; ++kh) {
        int cs = (kh * 4 + lg) ^ (row & 7);
        af[m][kh] = *reinterpret_cast<const short8*>(&As[row * 64 + cs * 8]);
      }
    }
#pragma unroll
    for (int n = 0; n < 2; ++n) {
      int row = wc * 32 + n * 16 + lr;
#pragma unroll
      for (int kh = 0; kh < 2; ++kh) {
        int cs = (kh * 4 + lg) ^ (row & 7);
        bfv[n][kh] = *reinterpret_cast<const short8*>(&Bs[row * 64 + cs * 8]);
      }
    }
#pragma unroll
    for (int kh = 0; kh < 2; ++kh)
#pragma unroll
      for (int m = 0; m < 4; ++m)
#pragma unroll
        for (int n = 0; n < 2; ++n)
          acc[m][n] = __builtin_amdgcn_mfma_f32_16x16x32_bf16(af[m][kh], bfv[n][kh], acc[m][n], 0, 0, 0);
  }

#pragma unroll
  for (int m = 0; m < 4; ++m)
#pragma unroll
    for (int n = 0; n < 2; ++n)
#pragma unroll
      for (int r = 0; r < 4; ++r) {
        int grow = bm * 128 + wr * 64 + m * 16 + lg * 4 + r;
        int gcol = bn * 64 + wc * 32 + n * 16 + lr;
        out[(size_t)grow * 1024 + gcol] = acc[m][n][r];
      }
}

// ---------------- fused distance-attention ----------------
// Wave owns 64 q-rows (2 x 32). Serial per-q-block softmax (lean regs, R8-verified);
// den via per-lane adds + shfl_xor(32). K-split x2 ONLY (R8's x4 was HBM-bound:
// 224MB partial traffic). PARTIAL: grid 512, 16 tiles/block, bf16-packed num.
template<bool PARTIAL>
__global__ __launch_bounds__(256) void attn_kernel(const unsigned short* __restrict__ qk,
                                                   const unsigned short* __restrict__ vt,
                                                   const float* __restrict__ q2lg_,
                                                   unsigned short* __restrict__ wout,
                                                   unsigned* __restrict__ num32,
                                                   float* __restrict__ denP) {
  __shared__ unsigned short Ks[2][64 * 64];
  __shared__ unsigned short Vs[2][64 * 64];
  __shared__ float q2L[2][64];
  __shared__ float invL[4][64];

  const int tid = threadIdx.x;
  const int chunk = PARTIAL ? 64 : 32;
  const int orig = (blockIdx.x & 7) * chunk + (blockIdx.x >> 3);
  const int half = PARTIAL ? (orig >> 8) : 0;
  const int rest = PARTIAL ? (orig & 255) : orig;
  const int bh = rest >> 3;          // 0..31
  const int qt = rest & 7;           // 8 q-tiles of 256 rows
  const int b = bh >> 4, h = bh & 15;
  const unsigned short* Qg = qk + (size_t)bh * Nc * 64;
  const unsigned short* Vg = vt + (size_t)bh * 64 * Nc;
  const float* q2lg = q2lg_ + (size_t)bh * Nc;
  const int lane = tid & 63, wid = tid >> 6;
  const int lo = lane & 31, hi = lane >> 5;

  const int qbase = qt * 256 + wid * 64;   // wave owns rows [qbase, qbase+64)
  const int kt0 = half * 16;
  const int ktn = PARTIAL ? 16 : 32;

  short8 qf0[4], qf1[4];
#pragma unroll
  for (int kk = 0; kk < 4; ++kk) {
    qf0[kk] = *reinterpret_cast<const short8*>(
        Qg + (size_t)(qbase + lo) * 64 + kk * 16 + hi * 8);
    qf1[kk] = *reinterpret_cast<const short8*>(
        Qg + (size_t)(qbase + 32 + lo) * 64 + kk * 16 + hi * 8);
  }
  const float q2l_r0 = q2lg[qbase + lo];
  const float q2l_r1 = q2lg[qbase + 32 + lo];

  f32x16 w00 = {}, w01 = {}, w10 = {}, w11 = {};
  float den0 = 0.f, den1 = 0.f;

  auto stage = [&](int kt, int s) {
#pragma unroll
    for (int r = 0; r < 2; ++r) {
      int idx = r * 256 + tid;
      int row = idx >> 3, cc = idx & 7;
      int cs = cc ^ (row & 7);
      gload_lds16(Qg + (size_t)(kt * 64 + row) * 64 + cs * 8,
                  &Ks[s][(r * 256 + wid * 64) * 8]);
      gload_lds16(Vg + (size_t)row * Nc + kt * 64 + cs * 8,
                  &Vs[s][(r * 256 + wid * 64) * 8]);
    }
    if (tid < 16) gload_lds16(q2lg + kt * 64 + tid * 4, &q2L[s][0]);
  };

  stage(kt0, 0);
  __syncthreads();

  for (int t = 0; t < ktn; ++t) {
    const int kt = kt0 + t;
    const int cur = t & 1;
    if (t + 1 < ktn) stage(kt + 1, cur ^ 1);

#pragma unroll
    for (int kg = 0; kg < 2; ++kg) {
      short8 kf[4];
#pragma unroll
      for (int kk = 0; kk < 4; ++kk) {
        int row = kg * 32 + lo;
        int c = (kk * 2 + hi) ^ (row & 7);
        kf[kk] = *reinterpret_cast<const short8*>(&Ks[cur][row * 64 + c * 8]);
      }

      unsigned pkA[8], pkB[8];
      {  // q-block 0
        f32x16 s = {};
        __builtin_amdgcn_s_setprio(1);
#pragma unroll
        for (int kk = 0; kk < 4; ++kk)
          s = __builtin_amdgcn_mfma_f32_32x32x16_bf16(kf[kk], qf0[kk], s, 0, 0, 0);
        __builtin_amdgcn_s_setprio(0);
#pragma unroll
        for (int q = 0; q < 4; ++q) {
          float4 k2q = *reinterpret_cast<const float4*>(&q2L[cur][kg * 32 + q * 8 + hi * 4]);
          float g[4];
#pragma unroll
          for (int rr = 0; rr < 4; ++rr) {
            float k2 = (rr == 0) ? k2q.x : (rr == 1) ? k2q.y : (rr == 2) ? k2q.z : k2q.w;
            g[rr] = fexp2(fmaf(s[q * 4 + rr], 2.0f * LOG2E, -(q2l_r0 + k2)));
            den0 += g[rr];
          }
          pkA[q * 2]     = cvt_pk_bf16(g[0], g[1]);
          pkA[q * 2 + 1] = cvt_pk_bf16(g[2], g[3]);
        }
      }
      {  // q-block 1
        f32x16 s = {};
        __builtin_amdgcn_s_setprio(1);
#pragma unroll
        for (int kk = 0; kk < 4; ++kk)
          s = __builtin_amdgcn_mfma_f32_32x32x16_bf16(kf[kk], qf1[kk], s, 0, 0, 0);
        __builtin_amdgcn_s_setprio(0);
#pragma unroll
        for (int q = 0; q < 4; ++q) {
          float4 k2q = *reinterpret_cast<const float4*>(&q2L[cur][kg * 32 + q * 8 + hi * 4]);
          float g[4];
#pragma unroll
          for (int rr = 0; rr < 4; ++rr) {
            float k2 = (rr == 0) ? k2q.x : (rr == 1) ? k2q.y : (rr == 2) ? k2q.z : k2q.w;
            g[rr] = fexp2(fmaf(s[q * 4 + rr], 2.0f * LOG2E, -(q2l_r1 + k2)));
            den1 += g[rr];
          }
          pkB[q * 2]     = cvt_pk_bf16(g[0], g[1]);
          pkB[q * 2 + 1] = cvt_pk_bf16(g[2], g[3]);
        }
      }

      // PV per 16-key sub-window; V-frags shared by both q-blocks.
      // permlane32_swap(a,b) -> {[a_lo,b_lo],[a_hi,b_hi]} (lane halves).
#pragma unroll
      for (int kkl = 0; kkl < 2; ++kkl) {
        uint2v r00 = __builtin_amdgcn_permlane32_swap(pkA[4 * kkl + 0], pkA[4 * kkl + 2], false, false);
        uint2v r01 = __builtin_amdgcn_permlane32_swap(pkA[4 * kkl + 1], pkA[4 * kkl + 3], false, false);
        uint2v r10 = __builtin_amdgcn_permlane32_swap(pkB[4 * kkl + 0], pkB[4 * kkl + 2], false, false);
        uint2v r11 = __builtin_amdgcn_permlane32_swap(pkB[4 * kkl + 1], pkB[4 * kkl + 3], false, false);
        uint4v u0; u0[0] = r00[0]; u0[1] = r01[0]; u0[2] = r00[1]; u0[3] = r01[1];
        uint4v u1; u1[0] = r10[0]; u1[1] = r11[0]; u1[2] = r10[1]; u1[3] = r11[1];
        short8 pa0 = __builtin_bit_cast(short8, u0);
        short8 pa1 = __builtin_bit_cast(short8, u1);

        __builtin_amdgcn_s_setprio(1);
#pragma unroll
        for (int dt = 0; dt < 2; ++dt) {
          int row = dt * 32 + lo;
          int c = (kg * 4 + kkl * 2 + hi) ^ (row & 7);
          short8 vfr = *reinterpret_cast<const short8*>(&Vs[cur][row * 64 + c * 8]);
          if (dt == 0) {
            w00 = __builtin_amdgcn_mfma_f32_32x32x16_bf16(pa0, vfr, w00, 0, 0, 0);
            w10 = __builtin_amdgcn_mfma_f32_32x32x16_bf16(pa1, vfr, w10, 0, 0, 0);
          } else {
            w01 = __builtin_amdgcn_mfma_f32_32x32x16_bf16(pa0, vfr, w01, 0, 0, 0);
            w11 = __builtin_amdgcn_mfma_f32_32x32x16_bf16(pa1, vfr, w11, 0, 0, 0);
          }
        }
        __builtin_amdgcn_s_setprio(0);
      }
    }
    __syncthreads();
  }

  den0 += __shfl_xor(den0, 32);
  den1 += __shfl_xor(den1, 32);

  if constexpr (PARTIAL) {
    unsigned* numh = num32 + (size_t)half * 65536 * 32;
    float* denh = denP + (size_t)half * 65536;
    const int rowb = bh * Nc + qbase;
    if (hi == 0) {
      denh[rowb + lo] = den0;
      denh[rowb + 32 + lo] = den1;
    }
#pragma unroll
    for (int reg = 0; reg < 16; ++reg) {
      int crow = (reg & 3) + 8 * (reg >> 2) + 4 * hi;
      numh[(size_t)(rowb + crow) * 32 + lo]      = cvt_pk_bf16(w00[reg], w01[reg]);
      numh[(size_t)(rowb + 32 + crow) * 32 + lo] = cvt_pk_bf16(w10[reg], w11[reg]);
    }
  } else {
    if (hi == 0) {
      invL[wid][lo]      = __builtin_amdgcn_rcpf(den0);
      invL[wid][32 + lo] = __builtin_amdgcn_rcpf(den1);
    }
    __syncthreads();
#pragma unroll
    for (int reg = 0; reg < 16; ++reg) {
      int crow = (reg & 3) + 8 * (reg >> 2) + 4 * hi;
      float iv0 = invL[wid][crow];
      float iv1 = invL[wid][32 + crow];
      size_t base0 = ((size_t)b * Nc + qbase + crow) * 1024 + h * 64 + lo;
      size_t base1 = ((size_t)b * Nc + qbase + 32 + crow) * 1024 + h * 64 + lo;
      wout[base0]      = f2bf(w00[reg] * iv0);
      wout[base0 + 32] = f2bf(w01[reg] * iv0);
      wout[base1]      = f2bf(w10[reg] * iv1);
      wout[base1 + 32] = f2bf(w11[reg] * iv1);
    }
  }
}

// -------- combine 2 partials: w = sum(num)/sum(den), scatter to (B,N,D) bf16 --------
__global__ __launch_bounds__(256) void combine_kernel(const unsigned* __restrict__ num32,
                                                      const float* __restrict__ denP,
                                                      unsigned short* __restrict__ wout) {
  int gid = blockIdx.x * 256 + threadIdx.x;   // 262144 threads
  int row = gid >> 2, quad = gid & 3;
  float iv = 1.0f / (denP[row] + denP[65536 + row]);
  float lo_[8] = {}, hi_[8] = {};
#pragma unroll
  for (int p = 0; p < 2; ++p) {
    const uint4v* np = reinterpret_cast<const uint4v*>(
        num32 + ((size_t)p * 65536 + row) * 32 + quad * 8);
    uint4v a = np[0], c = np[1];
#pragma unroll
    for (int j = 0; j < 4; ++j) {
      unsigned u = a[j];
      lo_[j] += bf2f((unsigned short)(u & 0xffff));
      hi_[j] += bf2f((unsigned short)(u >> 16));
      unsigned v = c[j];
      lo_[4 + j] += bf2f((unsigned short)(v & 0xffff));
      hi_[4 + j] += bf2f((unsigned short)(v >> 16));
    }
  }
  short8 o1, o2;
#pragma unroll
  for (int j = 0; j < 8; ++j) {
    o1[j] = (short)f2bf(lo_[j] * iv);
    o2[j] = (short)f2bf(hi_[j] * iv);
  }
  int bh = row >> 11, nn = row & 2047;
  int b = bh >> 4, h = bh & 15;
  size_t base = ((size_t)b * Nc + nn) * 1024 + h * 64;
  *reinterpret_cast<short8*>(&wout[base + quad * 8]) = o1;
  *reinterpret_cast<short8*>(&wout[base + 32 + quad * 8]) = o2;
}

extern "C" void kernel_launch(void* const* d_in, const int* in_sizes, int n_in,
                              void* d_out, int out_size, void* d_ws, size_t ws_size,
                              hipStream_t stream) {
  const float* x    = (const float*)d_in[0];
  const float* Wqk  = (const float*)d_in[1];
  const float* Wv   = (const float*)d_in[2];
  const float* Wout = (const float*)d_in[3];
  float* out = (float*)d_out;
  char* ws = (char*)d_ws;

  unsigned short* x_bf    = (unsigned short*)(ws + 0);          //  8 MB (dead after gemm_proj)
  unsigned short* wqk_bf  = (unsigned short*)(ws + 8388608);    //  2 MB
  unsigned short* wv_bf   = (unsigned short*)(ws + 10485760);   //  2 MB
  unsigned short* wout_bf = (unsigned short*)(ws + 12582912);   //  2 MB
  unsigned short* qk_buf  = (unsigned short*)(ws + 14680064);   //  8 MB (B,H,N,d)
  unsigned short* vt_buf  = (unsigned short*)(ws + 23068672);   //  8 MB (B,H,d,N)
  float*          q2l_buf = (float*)        (ws + 31457280);    // 256 KB
  unsigned short* w_buf   = (unsigned short*)(ws + 31719424);   //  8 MB (B,N,D)
  unsigned*       num_buf = (unsigned*)     (ws + 40108032);    // 16 MB (2 halves, bf16-packed)
  float*          den_buf = (float*)        (ws + 0);           // 512 KB (reuses dead x_bf region)
  const size_t need_split = 56885248;

  cvt_all<<<3584, 256, 0, stream>>>(x, Wqk, Wv, Wout, x_bf, wqk_bf, wv_bf, wout_bf);

  gemm_proj<<<512, 256, 0, stream>>>(x_bf, wqk_bf, wv_bf, qk_buf, vt_buf, q2l_buf);

  if (ws_size >= need_split) {
    attn_kernel<true><<<512, 256, 0, stream>>>(qk_buf, vt_buf, q2l_buf, nullptr, num_buf, den_buf);
    combine_kernel<<<1024, 256, 0, stream>>>(num_buf, den_buf, w_buf);
  } else {
    attn_kernel<false><<<256, 256, 0, stream>>>(qk_buf, vt_buf, q2l_buf, w_buf, nullptr, nullptr);
  }

  gemm_out<<<512, 256, 0, stream>>>(w_buf, wout_bf, out);
}

// Round 10
// 109.289 us; speedup vs baseline: 1.4044x; 1.0049x over previous
//
#include <hip/hip_runtime.h>

typedef __attribute__((ext_vector_type(8))) short short8;
typedef __attribute__((ext_vector_type(4))) float f32x4;
typedef __attribute__((ext_vector_type(16))) float f32x16;
typedef __attribute__((ext_vector_type(4))) unsigned short ushort4v;
typedef __attribute__((ext_vector_type(4))) unsigned int uint4v;
typedef __attribute__((ext_vector_type(2))) unsigned int uint2v;

constexpr int Nc = 2048, Kc = 1024;
constexpr float LOG2E = 1.4426950408889634f;

__device__ inline unsigned short f2bf(float f) {
  unsigned u = __builtin_bit_cast(unsigned, f);
  u = u + 0x7FFFu + ((u >> 16) & 1u);
  return (unsigned short)(u >> 16);
}
__device__ inline float bf2f(unsigned short h) {
  unsigned u = ((unsigned)h) << 16;
  return __builtin_bit_cast(float, u);
}
__device__ inline float fexp2(float x) {
  float r;
  asm("v_exp_f32 %0, %1" : "=v"(r) : "v"(x));
  return r;
}
__device__ inline unsigned cvt_pk_bf16(float lo, float hi) {
  unsigned r;
  asm("v_cvt_pk_bf16_f32 %0, %1, %2" : "=v"(r) : "v"(lo), "v"(hi));
  return r;
}

__device__ inline void gload_lds16(const void* g, void* l) {
  __builtin_amdgcn_global_load_lds(
      (const __attribute__((address_space(1))) unsigned int*)g,
      (__attribute__((address_space(3))) unsigned int*)l, 16, 0, 0);
}

// ---------------- fp32 -> bf16 convert, all 4 inputs in one launch ----------------
__global__ __launch_bounds__(256) void cvt_all(const float* __restrict__ x,
                                               const float* __restrict__ wqk,
                                               const float* __restrict__ wv,
                                               const float* __restrict__ wo,
                                               unsigned short* __restrict__ xb,
                                               unsigned short* __restrict__ wqkb,
                                               unsigned short* __restrict__ wvb,
                                               unsigned short* __restrict__ wob) {
  int bid = blockIdx.x;
  const float* src;
  unsigned short* dst;
  int i;
  if (bid < 2048) {
    src = x; dst = xb; i = bid * 256 + threadIdx.x;
  } else {
    int k = bid - 2048;
    int which = k >> 9, sub = k & 511;
    src = (which == 0) ? wqk : (which == 1) ? wv : wo;
    dst = (which == 0) ? wqkb : (which == 1) ? wvb : wob;
    i = sub * 256 + threadIdx.x;
  }
  const float4* s = reinterpret_cast<const float4*>(src) + 2 * (size_t)i;
  float4 a = s[0], b = s[1];
  short8 o;
  o[0] = (short)f2bf(a.x); o[1] = (short)f2bf(a.y); o[2] = (short)f2bf(a.z); o[3] = (short)f2bf(a.w);
  o[4] = (short)f2bf(b.x); o[5] = (short)f2bf(b.y); o[6] = (short)f2bf(b.z); o[7] = (short)f2bf(b.w);
  *reinterpret_cast<short8*>(dst + (size_t)i * 8) = o;
}

// ------- merged projection GEMM + fused q2: qk = x@Wqk^T (B,H,N,d), v^T (B,H,d,N) -------
__global__ __launch_bounds__(256) void gemm_proj(const unsigned short* __restrict__ A,
                                                 const unsigned short* __restrict__ Wqk,
                                                 const unsigned short* __restrict__ Wv,
                                                 unsigned short* __restrict__ qk_out,
                                                 unsigned short* __restrict__ vt_out,
                                                 float* __restrict__ q2l) {
  __shared__ unsigned short As[128 * 64];
  __shared__ unsigned short Bs[128 * 64];
  const int tid = threadIdx.x;
  const int bm = blockIdx.x & 31;
  const int bn = blockIdx.x >> 5;      // 0..15
  const bool isV = bn >= 8;
  const int lane = tid & 63, wid = tid >> 6;
  const int wr = wid >> 1, wc = wid & 1;
  const int lr = lane & 15, lg = lane >> 4;

  f32x4 acc[4][4] = {};

  const unsigned short* Abase = A + (size_t)bm * 128 * Kc;
  const unsigned short* Wbase = (isV ? Wv + (size_t)(bn - 8) * 128 * Kc
                                     : Wqk + (size_t)bn * 128 * Kc);

  for (int kt = 0; kt < Kc / 64; ++kt) {
    __syncthreads();
#pragma unroll
    for (int r = 0; r < 4; ++r) {
      int idx = r * 256 + tid;
      int row = idx >> 3, cc = idx & 7;
      int cs = cc ^ (row & 7);
      gload_lds16(Abase + (size_t)row * Kc + kt * 64 + cs * 8, &As[(r * 256 + wid * 64) * 8]);
      gload_lds16(Wbase + (size_t)row * Kc + kt * 64 + cs * 8, &Bs[(r * 256 + wid * 64) * 8]);
    }
    __syncthreads();

    short8 af[4][2], bfv[4][2];
#pragma unroll
    for (int m = 0; m < 4; ++m) {
      int row = wr * 64 + m * 16 + lr;
#pragma unroll
      for (int kh = 0; kh < 2; ++kh) {
        int cs = (kh * 4 + lg) ^ (row & 7);
        af[m][kh] = *reinterpret_cast<const short8*>(&As[row * 64 + cs * 8]);
      }
    }
#pragma unroll
    for (int n = 0; n < 4; ++n) {
      int row = wc * 64 + n * 16 + lr;
#pragma unroll
      for (int kh = 0; kh < 2; ++kh) {
        int cs = (kh * 4 + lg) ^ (row & 7);
        bfv[n][kh] = *reinterpret_cast<const short8*>(&Bs[row * 64 + cs * 8]);
      }
    }
#pragma unroll
    for (int kh = 0; kh < 2; ++kh)
#pragma unroll
      for (int m = 0; m < 4; ++m)
#pragma unroll
        for (int n = 0; n < 4; ++n)
          acc[m][n] = __builtin_amdgcn_mfma_f32_16x16x32_bf16(af[m][kh], bfv[n][kh], acc[m][n], 0, 0, 0);
  }

#pragma unroll
  for (int m = 0; m < 4; ++m) {
#pragma unroll
    for (int n = 0; n < 4; ++n) {
      int grow0 = bm * 128 + wr * 64 + m * 16 + lg * 4;
      int b = grow0 >> 11, nn0 = grow0 & 2047;
      if (isV) {
        int gcol = (bn - 8) * 128 + wc * 64 + n * 16 + lr;
        int h = gcol >> 6, dd = gcol & 63;
        ushort4v pk;
#pragma unroll
        for (int r = 0; r < 4; ++r) pk[r] = f2bf(acc[m][n][r]);
        *reinterpret_cast<ushort4v*>(&vt_out[(((size_t)(b * 16 + h)) * 64 + dd) * 2048 + nn0]) = pk;
      } else {
        int gcol = bn * 128 + wc * 64 + n * 16 + lr;
        int h = gcol >> 6, dd = gcol & 63;
#pragma unroll
        for (int r = 0; r < 4; ++r)
          qk_out[(((size_t)(b * 16 + h)) * 2048 + nn0 + r) * 64 + dd] = f2bf(acc[m][n][r]);
      }
    }
  }

  // fused q2: for qk blocks, wave wc holds all 64 d-cols of head h=2bn+wc
  if (!isV) {
    const int h = 2 * bn + wc;
#pragma unroll
    for (int m = 0; m < 4; ++m) {
#pragma unroll
      for (int r = 0; r < 4; ++r) {
        float ss = 0.f;
#pragma unroll
        for (int n = 0; n < 4; ++n) ss += acc[m][n][r] * acc[m][n][r];
        ss += __shfl_xor(ss, 1);
        ss += __shfl_xor(ss, 2);
        ss += __shfl_xor(ss, 4);
        ss += __shfl_xor(ss, 8);
        if (lr == 0) {
          int grow = bm * 128 + wr * 64 + m * 16 + lg * 4 + r;
          int b = grow >> 11, nn = grow & 2047;
          q2l[((size_t)(b * 16 + h)) * 2048 + nn] = ss * LOG2E;
        }
      }
    }
  }
}

// ------- output GEMM: out[m][e] = sum_k w[m][k] * Wout[e][k], fp32 out -------
__global__ __launch_bounds__(256) void gemm_out(const unsigned short* __restrict__ A,
                                                const unsigned short* __restrict__ W,
                                                float* __restrict__ out) {
  __shared__ unsigned short As[128 * 64];
  __shared__ unsigned short Bs[64 * 64];
  const int tid = threadIdx.x;
  const int bm = blockIdx.x & 31;
  const int bn = blockIdx.x >> 5;      // 0..15
  const int lane = tid & 63, wid = tid >> 6;
  const int wr = wid >> 1, wc = wid & 1;
  const int lr = lane & 15, lg = lane >> 4;

  f32x4 acc[4][2] = {};

  const unsigned short* Abase = A + (size_t)bm * 128 * Kc;
  const unsigned short* Wbase = W + (size_t)bn * 64 * Kc;

  for (int kt = 0; kt < Kc / 64; ++kt) {
    __syncthreads();
#pragma unroll
    for (int r = 0; r < 4; ++r) {
      int idx = r * 256 + tid;
      int row = idx >> 3, cc = idx & 7;
      int cs = cc ^ (row & 7);
      gload_lds16(Abase + (size_t)row * Kc + kt * 64 + cs * 8, &As[(r * 256 + wid * 64) * 8]);
    }
#pragma unroll
    for (int r = 0; r < 2; ++r) {
      int idx = r * 256 + tid;
      int row = idx >> 3, cc = idx & 7;
      int cs = cc ^ (row & 7);
      gload_lds16(Wbase + (size_t)row * Kc + kt * 64 + cs * 8, &Bs[(r * 256 + wid * 64) * 8]);
    }
    __syncthreads();

    short8 af[4][2], bfv[2][2];
#pragma unroll
    for (int m = 0; m < 4; ++m) {
      int row = wr * 64 + m * 16 + lr;
#pragma unroll
      for (int kh = 0; kh < 2; ++kh) {
        int cs = (kh * 4 + lg) ^ (row & 7);
        af[m][kh] = *reinterpret_cast<const short8*>(&As[row * 64 + cs * 8]);
      }
    }
#pragma unroll
    for (int n = 0; n < 2; ++n) {
      int row = wc * 32 + n * 16 + lr;
#pragma unroll
      for (int kh = 0; kh < 2; ++kh) {
        int cs = (kh * 4 + lg) ^ (row & 7);
        bfv[n][kh] = *reinterpret_cast<const short8*>(&Bs[row * 64 + cs * 8]);
      }
    }
#pragma unroll
    for (int kh = 0; kh < 2; ++kh)
#pragma unroll
      for (int m = 0; m < 4; ++m)
#pragma unroll
        for (int n = 0; n < 2; ++n)
          acc[m][n] = __builtin_amdgcn_mfma_f32_16x16x32_bf16(af[m][kh], bfv[n][kh], acc[m][n], 0, 0, 0);
  }

#pragma unroll
  for (int m = 0; m < 4; ++m)
#pragma unroll
    for (int n = 0; n < 2; ++n)
#pragma unroll
      for (int r = 0; r < 4; ++r) {
        int grow = bm * 128 + wr * 64 + m * 16 + lg * 4 + r;
        int gcol = bn * 64 + wc * 32 + n * 16 + lr;
        out[(size_t)grow * 1024 + gcol] = acc[m][n][r];
      }
}

// ---------------- fused distance-attention ----------------
// 2-wave blocks (128 thr), wave owns 64 q-rows. Grid 1024 (split x2) ->
// 3 blocks/CU (99KB LDS, ~168 regs) = 12 waves/CU vs R9's 8.
// Row term dropped from exponent: p' = exp2(2L*s - L*k2); the 2^(-L*q2row)
// factor is row-constant and cancels in num/den (incl. across halves).
template<bool PARTIAL>
__global__ __launch_bounds__(128) void attn_kernel(const unsigned short* __restrict__ qk,
                                                   const unsigned short* __restrict__ vt,
                                                   const float* __restrict__ q2lg_,
                                                   unsigned short* __restrict__ wout,
                                                   unsigned* __restrict__ num32,
                                                   float* __restrict__ denP) {
  __shared__ unsigned short Ks[2][64 * 64];
  __shared__ unsigned short Vs[2][64 * 64];
  __shared__ float q2L[2][64];
  __shared__ float invL[2][64];

  const int tid = threadIdx.x;
  const int chunk = PARTIAL ? 128 : 64;
  const int orig = (blockIdx.x & 7) * chunk + (blockIdx.x >> 3);
  const int half = PARTIAL ? (orig >> 9) : 0;
  const int rest = PARTIAL ? (orig & 511) : orig;
  const int bh = rest >> 4;          // 0..31
  const int qt = rest & 15;          // 16 q-tiles of 128 rows
  const int b = bh >> 4, h = bh & 15;
  const unsigned short* Qg = qk + (size_t)bh * Nc * 64;
  const unsigned short* Vg = vt + (size_t)bh * 64 * Nc;
  const float* q2lg = q2lg_ + (size_t)bh * Nc;
  const int lane = tid & 63, wid = tid >> 6;
  const int lo = lane & 31, hi = lane >> 5;

  const int qbase = qt * 128 + wid * 64;   // wave owns rows [qbase, qbase+64)
  const int kt0 = half * 16;
  const int ktn = PARTIAL ? 16 : 32;

  short8 qf0[4], qf1[4];
#pragma unroll
  for (int kk = 0; kk < 4; ++kk) {
    qf0[kk] = *reinterpret_cast<const short8*>(
        Qg + (size_t)(qbase + lo) * 64 + kk * 16 + hi * 8);
    qf1[kk] = *reinterpret_cast<const short8*>(
        Qg + (size_t)(qbase + 32 + lo) * 64 + kk * 16 + hi * 8);
  }

  f32x16 w00 = {}, w01 = {}, w10 = {}, w11 = {};
  float den0 = 0.f, den1 = 0.f;

  auto stage = [&](int kt, int s) {
#pragma unroll
    for (int r = 0; r < 4; ++r) {
      int idx = r * 128 + tid;
      int row = idx >> 3, cc = idx & 7;
      int cs = cc ^ (row & 7);
      gload_lds16(Qg + (size_t)(kt * 64 + row) * 64 + cs * 8,
                  &Ks[s][(r * 128 + wid * 64) * 8]);
      gload_lds16(Vg + (size_t)row * Nc + kt * 64 + cs * 8,
                  &Vs[s][(r * 128 + wid * 64) * 8]);
    }
    if (tid < 16) gload_lds16(q2lg + kt * 64 + tid * 4, &q2L[s][0]);
  };

  stage(kt0, 0);
  __syncthreads();

  for (int t = 0; t < ktn; ++t) {
    const int kt = kt0 + t;
    const int cur = t & 1;
    if (t + 1 < ktn) stage(kt + 1, cur ^ 1);

#pragma unroll
    for (int kg = 0; kg < 2; ++kg) {
      short8 kf[4];
#pragma unroll
      for (int kk = 0; kk < 4; ++kk) {
        int row = kg * 32 + lo;
        int c = (kk * 2 + hi) ^ (row & 7);
        kf[kk] = *reinterpret_cast<const short8*>(&Ks[cur][row * 64 + c * 8]);
      }

      unsigned pkA[8], pkB[8];
      {  // q-block 0
        f32x16 s = {};
        __builtin_amdgcn_s_setprio(1);
#pragma unroll
        for (int kk = 0; kk < 4; ++kk)
          s = __builtin_amdgcn_mfma_f32_32x32x16_bf16(kf[kk], qf0[kk], s, 0, 0, 0);
        __builtin_amdgcn_s_setprio(0);
#pragma unroll
        for (int q = 0; q < 4; ++q) {
          float4 k2q = *reinterpret_cast<const float4*>(&q2L[cur][kg * 32 + q * 8 + hi * 4]);
          float g[4];
#pragma unroll
          for (int rr = 0; rr < 4; ++rr) {
            float k2 = (rr == 0) ? k2q.x : (rr == 1) ? k2q.y : (rr == 2) ? k2q.z : k2q.w;
            g[rr] = fexp2(fmaf(s[q * 4 + rr], 2.0f * LOG2E, -k2));
            den0 += g[rr];
          }
          pkA[q * 2]     = cvt_pk_bf16(g[0], g[1]);
          pkA[q * 2 + 1] = cvt_pk_bf16(g[2], g[3]);
        }
      }
      {  // q-block 1
        f32x16 s = {};
        __builtin_amdgcn_s_setprio(1);
#pragma unroll
        for (int kk = 0; kk < 4; ++kk)
          s = __builtin_amdgcn_mfma_f32_32x32x16_bf16(kf[kk], qf1[kk], s, 0, 0, 0);
        __builtin_amdgcn_s_setprio(0);
#pragma unroll
        for (int q = 0; q < 4; ++q) {
          float4 k2q = *reinterpret_cast<const float4*>(&q2L[cur][kg * 32 + q * 8 + hi * 4]);
          float g[4];
#pragma unroll
          for (int rr = 0; rr < 4; ++rr) {
            float k2 = (rr == 0) ? k2q.x : (rr == 1) ? k2q.y : (rr == 2) ? k2q.z : k2q.w;
            g[rr] = fexp2(fmaf(s[q * 4 + rr], 2.0f * LOG2E, -k2));
            den1 += g[rr];
          }
          pkB[q * 2]     = cvt_pk_bf16(g[0], g[1]);
          pkB[q * 2 + 1] = cvt_pk_bf16(g[2], g[3]);
        }
      }

      // PV per 16-key sub-window; V-frags shared by both q-blocks.
      // permlane32_swap(a,b) -> {[a_lo,b_lo],[a_hi,b_hi]} (lane halves).
#pragma unroll
      for (int kkl = 0; kkl < 2; ++kkl) {
        uint2v r00 = __builtin_amdgcn_permlane32_swap(pkA[4 * kkl + 0], pkA[4 * kkl + 2], false, false);
        uint2v r01 = __builtin_amdgcn_permlane32_swap(pkA[4 * kkl + 1], pkA[4 * kkl + 3], false, false);
        uint2v r10 = __builtin_amdgcn_permlane32_swap(pkB[4 * kkl + 0], pkB[4 * kkl + 2], false, false);
        uint2v r11 = __builtin_amdgcn_permlane32_swap(pkB[4 * kkl + 1], pkB[4 * kkl + 3], false, false);
        uint4v u0; u0[0] = r00[0]; u0[1] = r01[0]; u0[2] = r00[1]; u0[3] = r01[1];
        uint4v u1; u1[0] = r10[0]; u1[1] = r11[0]; u1[2] = r10[1]; u1[3] = r11[1];
        short8 pa0 = __builtin_bit_cast(short8, u0);
        short8 pa1 = __builtin_bit_cast(short8, u1);

        __builtin_amdgcn_s_setprio(1);
#pragma unroll
        for (int dt = 0; dt < 2; ++dt) {
          int row = dt * 32 + lo;
          int c = (kg * 4 + kkl * 2 + hi) ^ (row & 7);
          short8 vfr = *reinterpret_cast<const short8*>(&Vs[cur][row * 64 + c * 8]);
          if (dt == 0) {
            w00 = __builtin_amdgcn_mfma_f32_32x32x16_bf16(pa0, vfr, w00, 0, 0, 0);
            w10 = __builtin_amdgcn_mfma_f32_32x32x16_bf16(pa1, vfr, w10, 0, 0, 0);
          } else {
            w01 = __builtin_amdgcn_mfma_f32_32x32x16_bf16(pa0, vfr, w01, 0, 0, 0);
            w11 = __builtin_amdgcn_mfma_f32_32x32x16_bf16(pa1, vfr, w11, 0, 0, 0);
          }
        }
        __builtin_amdgcn_s_setprio(0);
      }
    }
    __syncthreads();
  }

  den0 += __shfl_xor(den0, 32);
  den1 += __shfl_xor(den1, 32);

  if constexpr (PARTIAL) {
    unsigned* numh = num32 + (size_t)half * 65536 * 32;
    float* denh = denP + (size_t)half * 65536;
    const int rowb = bh * Nc + qbase;
    if (hi == 0) {
      denh[rowb + lo] = den0;
      denh[rowb + 32 + lo] = den1;
    }
#pragma unroll
    for (int reg = 0; reg < 16; ++reg) {
      int crow = (reg & 3) + 8 * (reg >> 2) + 4 * hi;
      numh[(size_t)(rowb + crow) * 32 + lo]      = cvt_pk_bf16(w00[reg], w01[reg]);
      numh[(size_t)(rowb + 32 + crow) * 32 + lo] = cvt_pk_bf16(w10[reg], w11[reg]);
    }
  } else {
    if (hi == 0) {
      invL[wid][lo]      = __builtin_amdgcn_rcpf(den0);
      invL[wid][32 + lo] = __builtin_amdgcn_rcpf(den1);
    }
    __syncthreads();
#pragma unroll
    for (int reg = 0; reg < 16; ++reg) {
      int crow = (reg & 3) + 8 * (reg >> 2) + 4 * hi;
      float iv0 = invL[wid][crow];
      float iv1 = invL[wid][32 + crow];
      size_t base0 = ((size_t)b * Nc + qbase + crow) * 1024 + h * 64 + lo;
      size_t base1 = ((size_t)b * Nc + qbase + 32 + crow) * 1024 + h * 64 + lo;
      wout[base0]      = f2bf(w00[reg] * iv0);
      wout[base0 + 32] = f2bf(w01[reg] * iv0);
      wout[base1]      = f2bf(w10[reg] * iv1);
      wout[base1 + 32] = f2bf(w11[reg] * iv1);
    }
  }
}

// -------- combine 2 partials: w = sum(num)/sum(den), scatter to (B,N,D) bf16 --------
__global__ __launch_bounds__(256) void combine_kernel(const unsigned* __restrict__ num32,
                                                      const float* __restrict__ denP,
                                                      unsigned short* __restrict__ wout) {
  int gid = blockIdx.x * 256 + threadIdx.x;   // 262144 threads
  int row = gid >> 2, quad = gid & 3;
  float iv = 1.0f / (denP[row] + denP[65536 + row]);
  float lo_[8] = {}, hi_[8] = {};
#pragma unroll
  for (int p = 0; p < 2; ++p) {
    const uint4v* np = reinterpret_cast<const uint4v*>(
        num32 + ((size_t)p * 65536 + row) * 32 + quad * 8);
    uint4v a = np[0], c = np[1];
#pragma unroll
    for (int j = 0; j < 4; ++j) {
      unsigned u = a[j];
      lo_[j] += bf2f((unsigned short)(u & 0xffff));
      hi_[j] += bf2f((unsigned short)(u >> 16));
      unsigned v = c[j];
      lo_[4 + j] += bf2f((unsigned short)(v & 0xffff));
      hi_[4 + j] += bf2f((unsigned short)(v >> 16));
    }
  }
  short8 o1, o2;
#pragma unroll
  for (int j = 0; j < 8; ++j) {
    o1[j] = (short)f2bf(lo_[j] * iv);
    o2[j] = (short)f2bf(hi_[j] * iv);
  }
  int bh = row >> 11, nn = row & 2047;
  int b = bh >> 4, h = bh & 15;
  size_t base = ((size_t)b * Nc + nn) * 1024 + h * 64;
  *reinterpret_cast<short8*>(&wout[base + quad * 8]) = o1;
  *reinterpret_cast<short8*>(&wout[base + 32 + quad * 8]) = o2;
}

extern "C" void kernel_launch(void* const* d_in, const int* in_sizes, int n_in,
                              void* d_out, int out_size, void* d_ws, size_t ws_size,
                              hipStream_t stream) {
  const float* x    = (const float*)d_in[0];
  const float* Wqk  = (const float*)d_in[1];
  const float* Wv   = (const float*)d_in[2];
  const float* Wout = (const float*)d_in[3];
  float* out = (float*)d_out;
  char* ws = (char*)d_ws;

  unsigned short* x_bf    = (unsigned short*)(ws + 0);          //  8 MB (dead after gemm_proj)
  unsigned short* wqk_bf  = (unsigned short*)(ws + 8388608);    //  2 MB
  unsigned short* wv_bf   = (unsigned short*)(ws + 10485760);   //  2 MB
  unsigned short* wout_bf = (unsigned short*)(ws + 12582912);   //  2 MB
  unsigned short* qk_buf  = (unsigned short*)(ws + 14680064);   //  8 MB (B,H,N,d)
  unsigned short* vt_buf  = (unsigned short*)(ws + 23068672);   //  8 MB (B,H,d,N)
  float*          q2l_buf = (float*)        (ws + 31457280);    // 256 KB
  unsigned short* w_buf   = (unsigned short*)(ws + 31719424);   //  8 MB (B,N,D)
  unsigned*       num_buf = (unsigned*)     (ws + 40108032);    // 16 MB (2 halves, bf16-packed)
  float*          den_buf = (float*)        (ws + 0);           // 512 KB (reuses dead x_bf region)
  const size_t need_split = 56885248;

  cvt_all<<<3584, 256, 0, stream>>>(x, Wqk, Wv, Wout, x_bf, wqk_bf, wv_bf, wout_bf);

  gemm_proj<<<512, 256, 0, stream>>>(x_bf, wqk_bf, wv_bf, qk_buf, vt_buf, q2l_buf);

  if (ws_size >= need_split) {
    attn_kernel<true><<<1024, 128, 0, stream>>>(qk_buf, vt_buf, q2l_buf, nullptr, num_buf, den_buf);
    combine_kernel<<<1024, 256, 0, stream>>>(num_buf, den_buf, w_buf);
  } else {
    attn_kernel<false><<<512, 128, 0, stream>>>(qk_buf, vt_buf, q2l_buf, w_buf, nullptr, nullptr);
  }

  gemm_out<<<512, 256, 0, stream>>>(w_buf, wout_bf, out);
}